// Round 7
// baseline (123.224 us; speedup 1.0000x reference)
//
#include <hip/hip_runtime.h>
#include <math.h>

#define BS 8
#define P 8192
#define G 16
#define DIM 512

#define BLOCK 256
#define WAVES 4                 // waves per block
#define RPG 4                   // rows per 8-lane group
#define ROWS_PER_WAVE (8 * RPG)                 // 32
#define ROWS_PER_BLOCK (WAVES * ROWS_PER_WAVE) // 128
#define BLOCKS_PER_BATCH (P / ROWS_PER_BLOCK)  // 64  -> grid 512 = 2 blocks/CU
#define BIGSTEPS 8              // per step a lane covers 8 cols (2x float4)

__device__ __forceinline__ float smooth_l1(float d) {
    float a = fabsf(d);
    return a < 1.0f ? 0.5f * d * d : a - 0.5f;
}

__device__ __forceinline__ float dot4(float4 a, float4 b) {
    return a.x * b.x + a.y * b.y + a.z * b.z + a.w * b.w;
}

// launch_bounds min-waves/EU = 1 (VGPR cap 512). Occupancy is fixed by the
// 512-block grid (2 blocks/CU = 2 waves/SIMD); any VGPR count <= 256 is free.
// The ",4"/",2" bounds made the allocator clamp to 64 VGPR and spill
// (125-421 MB scratch writes in r2-r4). The 4-deep prefetch below NEEDS
// ~128 VGPRs of loads in flight (Little's law: ~512B/wave outstanding to
// reach ~5 TB/s at ~500cy L3 latency).
__global__ __launch_bounds__(BLOCK, 1)
void det_main(const float* __restrict__ v,
              const float* __restrict__ gt,
              const float* __restrict__ rois,
              const float* __restrict__ labels,
              const float* __restrict__ pre_score,
              const float* __restrict__ cls_w,
              const float* __restrict__ cls_b,
              const float* __restrict__ reg_w,
              const float* __restrict__ reg_b,
              float* __restrict__ partials)   // [BS][3]: cnum, cden, l1
{
    const int tid  = threadIdx.x;
    const int lane = tid & 63;
    const int wave = tid >> 6;
    const int l    = lane & 7;   // lane within group
    const int grp  = lane >> 3;  // group within wave (0..7)
    const int b    = blockIdx.x / BLOCKS_PER_BATCH;
    const int blk  = blockIdx.x % BLOCKS_PER_BATCH;
    const int p0   = blk * ROWS_PER_BLOCK + wave * ROWS_PER_WAVE + grp * RPG;

    __shared__ float s_w[8 * DIM];   // 16 KB: c=0..3 cls, c=4..7 reg
    __shared__ float s_gt[G * 4];
    __shared__ int   s_lab;
    __shared__ float s_red[WAVES][3];

    // ---- stage weights into LDS (flat float4 copy)
    {
        const float4* cw = (const float4*)cls_w;   // 512 float4
        const float4* rw = (const float4*)reg_w;   // 512 float4
        float4* sw = (float4*)s_w;
        #pragma unroll
        for (int i = 0; i < 2; ++i) sw[i * BLOCK + tid]       = cw[i * BLOCK + tid];
        #pragma unroll
        for (int i = 0; i < 2; ++i) sw[512 + i * BLOCK + tid] = rw[i * BLOCK + tid];
    }
    if (tid < G * 4) s_gt[tid] = gt[b * G * 4 + tid];
    if (tid == 0) {
        const float* lb = labels + b * 4;
        int li = 0; float lm = lb[0];
        #pragma unroll
        for (int i = 1; i < 4; ++i) if (lb[i] > lm) { lm = lb[i]; li = i; }
        s_lab = li;
    }
    __syncthreads();
    const int lab = s_lab;

    // ---- hoisted epilogue loads (latency hides under GEMV)
    float4 rbox = make_float4(0.f, 0.f, 0.f, 1.f);
    float ps = 0.0f;
    if (l < RPG) {
        const int p = p0 + l;
        rbox = *(const float4*)(rois + ((size_t)b * P + p) * 4);
        ps   = pre_score[((size_t)b * P + p) * 4 + lab];
    }

    const float cb0 = cls_b[0], cb1 = cls_b[1], cb2 = cls_b[2], cb3 = cls_b[3];
    const float rb0 = reg_b[0], rb1 = reg_b[1], rb2 = reg_b[2], rb3 = reg_b[3];

    // ---- GEMV: acc[c][r] = partial dot of row (p0+r) with matrix c
    float acc[8][RPG];
    #pragma unroll
    for (int c = 0; c < 8; ++c)
        #pragma unroll
        for (int r = 0; r < RPG; ++r) acc[c][r] = 0.0f;

    // step s covers cols [s*64, s*64+64): f4 #0 at l*4 + s*64 (128B span per
    // group), f4 #1 at l*4 + 32 + s*64 (second contiguous 128B span).
    const float* vb = v + ((size_t)b * P + p0) * DIM + l * 4;

    // 4-deep rotating prefetch: 4 bufs x 4 rows x 2 float4 = 128 VGPR in flight
    float4 buf[4][RPG][2];
    #pragma unroll
    for (int s = 0; s < 4; ++s)
        #pragma unroll
        for (int r = 0; r < RPG; ++r) {
            buf[s][r][0] = *(const float4*)(vb + r * DIM + s * 64);
            buf[s][r][1] = *(const float4*)(vb + r * DIM + s * 64 + 32);
        }

    #pragma unroll
    for (int s = 0; s < BIGSTEPS; ++s) {
        const int sb = s & 3;   // compile-time after full unroll
        // two halves of 4 weight vectors -> bounded transient pressure
        #pragma unroll
        for (int h = 0; h < 2; ++h) {
            float4 w0[4], w1[4];
            #pragma unroll
            for (int c = 0; c < 4; ++c) {
                w0[c] = *(const float4*)&s_w[(h * 4 + c) * DIM + l * 4 + s * 64];
                w1[c] = *(const float4*)&s_w[(h * 4 + c) * DIM + l * 4 + 32 + s * 64];
            }
            #pragma unroll
            for (int c = 0; c < 4; ++c)
                #pragma unroll
                for (int r = 0; r < RPG; ++r)
                    acc[h * 4 + c][r] += dot4(w0[c], buf[sb][r][0])
                                       + dot4(w1[c], buf[sb][r][1]);
        }
        // refill this buffer for step s+4
        if (s + 4 < BIGSTEPS) {
            #pragma unroll
            for (int r = 0; r < RPG; ++r) {
                buf[sb][r][0] = *(const float4*)(vb + r * DIM + (s + 4) * 64);
                buf[sb][r][1] = *(const float4*)(vb + r * DIM + (s + 4) * 64 + 32);
            }
        }
    }

    // ---- reduce across the 8 lanes of each group (3 butterfly steps)
    #pragma unroll
    for (int c = 0; c < 8; ++c)
        #pragma unroll
        for (int r = 0; r < RPG; ++r) {
            float x = acc[c][r];
            x += __shfl_xor(x, 1);
            x += __shfl_xor(x, 2);
            x += __shfl_xor(x, 4);
            acc[c][r] = x;
        }

    // ---- epilogue: lane l (<RPG) of each group handles row p0+l
    float acc_cnum = 0.0f, acc_cden = 0.0f, acc_l1 = 0.0f;
    if (l < RPG) {
        float d[8];
        #pragma unroll
        for (int r = 0; r < RPG; ++r)
            if (l == r) {
                #pragma unroll
                for (int c = 0; c < 8; ++c) d[c] = acc[c][r];
            }
        const float area_r = (rbox.z - rbox.x) * (rbox.w - rbox.y);

        float biou = -1.0f; int bidx = 0;
        #pragma unroll
        for (int gi = 0; gi < G; ++gi) {
            float g0 = s_gt[gi * 4 + 0], g1 = s_gt[gi * 4 + 1];
            float g2 = s_gt[gi * 4 + 2], g3 = s_gt[gi * 4 + 3];
            float ltx = fmaxf(g0, rbox.x), lty = fmaxf(g1, rbox.y);
            float rbx = fminf(g2, rbox.z), rby = fminf(g3, rbox.w);
            float wx = fmaxf(rbx - ltx, 0.0f), wy = fmaxf(rby - lty, 0.0f);
            float inter = wx * wy;
            float ag = (g2 - g0) * (g3 - g1);
            float iou = inter / (ag + area_r - inter);
            if (iou > biou) { biou = iou; bidx = gi; }
        }
        const float mask = biou > 0.5f ? 1.0f : 0.0f;

        // cross-entropy on clipped logits
        float c0 = fminf(fmaxf(d[0] + cb0, 1e-7f), 0.99999994f);
        float c1 = fminf(fmaxf(d[1] + cb1, 1e-7f), 0.99999994f);
        float c2 = fminf(fmaxf(d[2] + cb2, 1e-7f), 0.99999994f);
        float c3 = fminf(fmaxf(d[3] + cb3, 1e-7f), 0.99999994f);
        float m  = fmaxf(fmaxf(c0, c1), fmaxf(c2, c3));
        float s  = expf(c0 - m) + expf(c1 - m) + expf(c2 - m) + expf(c3 - m);
        float lse = m + logf(s);
        float csel = lab == 0 ? c0 : (lab == 1 ? c1 : (lab == 2 ? c2 : c3));
        float ce = lse - csel;

        acc_cnum = ce * ps * mask;
        acc_cden = mask;

        // regression loss vs best-GT targets
        float bg0 = s_gt[bidx * 4 + 0], bg1 = s_gt[bidx * 4 + 1];
        float bg2 = s_gt[bidx * 4 + 2], bg3 = s_gt[bidx * 4 + 3];
        float gx = (bg2 + bg0) * 0.5f, gy = (bg3 + bg1) * 0.5f;
        float gw = (bg2 - bg0) * 0.5f, gh = (bg3 - bg1) * 0.5f;
        float rx = (rbox.z + rbox.x) * 0.5f, ry = (rbox.w + rbox.y) * 0.5f;
        float rw_ = (rbox.z - rbox.x) * 0.5f, rh = (rbox.w - rbox.y) * 0.5f;
        float tx = (gx - rx) / (rw_ + 1e-8f);
        float ty = (gy - ry) / (rh + 1e-8f);
        float tw = logf(gw / (rw_ + 1e-8f));
        float th = logf(gh / (rh + 1e-8f));
        float l1v = smooth_l1(d[4] + rb0 - tx) + smooth_l1(d[5] + rb1 - ty)
                  + smooth_l1(d[6] + rb2 - tw) + smooth_l1(d[7] + rb3 - th);
        acc_l1 = l1v * mask * ps;
    }

    // ---- full-wave butterfly sum of the three partials
    #pragma unroll
    for (int off = 32; off > 0; off >>= 1) {
        acc_cnum += __shfl_xor(acc_cnum, off);
        acc_cden += __shfl_xor(acc_cden, off);
        acc_l1   += __shfl_xor(acc_l1,   off);
    }
    if (lane == 0) {
        s_red[wave][0] = acc_cnum;
        s_red[wave][1] = acc_cden;
        s_red[wave][2] = acc_l1;
    }
    __syncthreads();
    if (tid == 0) {
        float a = 0.0f, bb = 0.0f, cc = 0.0f;
        #pragma unroll
        for (int wv = 0; wv < WAVES; ++wv) {
            a  += s_red[wv][0];
            bb += s_red[wv][1];
            cc += s_red[wv][2];
        }
        atomicAdd(&partials[b * 3 + 0], a);
        atomicAdd(&partials[b * 3 + 1], bb);
        atomicAdd(&partials[b * 3 + 2], cc);
    }
}

__global__ void det_final(const float* __restrict__ partials, float* __restrict__ out)
{
    if (threadIdx.x == 0 && blockIdx.x == 0) {
        float cl = 0.0f, l1 = 0.0f;
        #pragma unroll
        for (int b = 0; b < BS; ++b) {
            cl += partials[b * 3 + 0] / (partials[b * 3 + 1] + 1e-7f);
            l1 += partials[b * 3 + 2];
        }
        out[0] = cl / ((float)BS + 1e-7f) + l1 / (float)(BS * P);
    }
}

extern "C" void kernel_launch(void* const* d_in, const int* in_sizes, int n_in,
                              void* d_out, int out_size, void* d_ws, size_t ws_size,
                              hipStream_t stream) {
    const float* v         = (const float*)d_in[0];
    const float* gt        = (const float*)d_in[1];
    const float* rois      = (const float*)d_in[2];
    const float* labels    = (const float*)d_in[3];
    const float* pre_score = (const float*)d_in[4];
    const float* cls_w     = (const float*)d_in[5];
    const float* cls_b     = (const float*)d_in[6];
    const float* reg_w     = (const float*)d_in[7];
    const float* reg_b     = (const float*)d_in[8];
    float* partials = (float*)d_ws;
    float* out      = (float*)d_out;

    hipMemsetAsync(d_ws, 0, BS * 3 * sizeof(float), stream);
    det_main<<<(BS * P) / ROWS_PER_BLOCK, BLOCK, 0, stream>>>(
        v, gt, rois, labels, pre_score, cls_w, cls_b, reg_w, reg_b, partials);
    det_final<<<1, 64, 0, stream>>>(partials, out);
}

// Round 8
// 86.873 us; speedup vs baseline: 1.4184x; 1.4184x over previous
//
#include <hip/hip_runtime.h>
#include <math.h>

#define BS 8
#define P 8192
#define G 16
#define DIM 512

#define BLOCK 256
#define WAVES 4
#define CHUNK_ROWS 8                            // rows staged per chunk
#define RPW 2                                   // rows per wave per chunk
#define NCHUNK 8                                // chunks per block
#define ROWS_PER_BLOCK (CHUNK_ROWS * NCHUNK)    // 64 -> grid 1024
#define BLOCKS_PER_BATCH (P / ROWS_PER_BLOCK)   // 128
#define KS (DIM / 128)                          // 4 k-steps (32 lanes x 4 floats)

__device__ __forceinline__ float smooth_l1(float d) {
    float a = fabsf(d);
    return a < 1.0f ? 0.5f * d * d : a - 0.5f;
}

__device__ __forceinline__ float dot4(float4 a, float4 b) {
    return a.x * b.x + a.y * b.y + a.z * b.z + a.w * b.w;
}

// Fire-and-forget global->LDS DMA, 16B per lane. LDS dest = uniform base +
// lane*16 (HW-implicit). In-flight bytes live in the memory system, not VGPRs
// -- this is the concurrency unlock (r2..r7 register prefetch either starved
// at ~1KB/CU in flight or spilled past 256 VGPRs).
__device__ __forceinline__ void load16_to_lds(const float* gsrc, float* ldst) {
    __builtin_amdgcn_global_load_lds(
        (const __attribute__((address_space(1))) void*)gsrc,
        (__attribute__((address_space(3))) void*)ldst,
        16, 0, 0);
}

__global__ __launch_bounds__(BLOCK, 1)
void det_main(const float* __restrict__ v,
              const float* __restrict__ gt,
              const float* __restrict__ rois,
              const float* __restrict__ labels,
              const float* __restrict__ pre_score,
              const float* __restrict__ cls_w,
              const float* __restrict__ cls_b,
              const float* __restrict__ reg_w,
              const float* __restrict__ reg_b,
              float* __restrict__ partials)   // [BS][3]: cnum, cden, l1
{
    const int tid  = threadIdx.x;
    const int lane = tid & 63;
    const int w    = tid >> 6;      // wave 0..3
    const int g    = lane >> 5;     // row-group within wave (0..1)
    const int lg   = lane & 31;     // lane within row-group
    const int b    = blockIdx.x / BLOCKS_PER_BATCH;
    const int blk  = blockIdx.x % BLOCKS_PER_BATCH;
    const int p0   = blk * ROWS_PER_BLOCK;

    __shared__ float s_w[8 * DIM];                  // 16 KB weights
    __shared__ float s_v[2][CHUNK_ROWS * DIM];      // 2 x 16 KB chunk buffers
    __shared__ float s_gt[G * 4];
    __shared__ int   s_lab;
    __shared__ float s_red[WAVES][3];

    const float* vblock = v + ((size_t)b * P + p0) * DIM;

    // ---- issue chunk-0 DMA immediately (latency hides under weight setup).
    // Wave w stages ONLY its own rows [w*RPW, w*RPW+RPW) of each chunk.
    {
        const float* src = vblock + w * (RPW * DIM);
        float* dst = &s_v[0][w * (RPW * DIM)];
        #pragma unroll
        for (int j = 0; j < 4; ++j)
            load16_to_lds(src + j * 256 + lane * 4, dst + j * 256);
    }

    // ---- stage weights into LDS (flat float4 copy)
    {
        const float4* cw = (const float4*)cls_w;   // 512 float4
        const float4* rw = (const float4*)reg_w;   // 512 float4
        float4* sw = (float4*)s_w;
        #pragma unroll
        for (int i = 0; i < 2; ++i) sw[i * BLOCK + tid]       = cw[i * BLOCK + tid];
        #pragma unroll
        for (int i = 0; i < 2; ++i) sw[512 + i * BLOCK + tid] = rw[i * BLOCK + tid];
    }
    if (tid < G * 4) s_gt[tid] = gt[b * G * 4 + tid];
    if (tid == 0) {
        const float* lb = labels + b * 4;
        int li = 0; float lm = lb[0];
        #pragma unroll
        for (int i = 1; i < 4; ++i) if (lb[i] > lm) { lm = lb[i]; li = i; }
        s_lab = li;
    }
    __syncthreads();
    const int lab = s_lab;

    const float cb0 = cls_b[0], cb1 = cls_b[1], cb2 = cls_b[2], cb3 = cls_b[3];
    const float rb0 = reg_b[0], rb1 = reg_b[1], rb2 = reg_b[2], rb3 = reg_b[3];

    const int rl = w * RPW + g;      // this lane's local row within a chunk

    float acc_cnum = 0.0f, acc_cden = 0.0f, acc_l1 = 0.0f;

    for (int c = 0; c < NCHUNK; ++c) {
        const int bb = c & 1;
        const int p  = p0 + c * CHUNK_ROWS + rl;   // global row (within batch)

        // epilogue operands for this chunk -- issued early, drained by vmcnt
        float4 rbox = make_float4(0.f, 0.f, 0.f, 1.f);
        float  ps   = 0.0f;
        if (lg == 0) {
            rbox = *(const float4*)(rois + ((size_t)b * P + p) * 4);
            ps   = pre_score[((size_t)b * P + p) * 4 + lab];
        }

        // prefetch next chunk via DMA, then wait ONLY for the current chunk
        // (counted vmcnt -- next chunk's 4 issues stay in flight)
        if (c + 1 < NCHUNK) {
            const float* src = vblock + (c + 1) * (CHUNK_ROWS * DIM) + w * (RPW * DIM);
            float* dst = &s_v[bb ^ 1][w * (RPW * DIM)];
            #pragma unroll
            for (int j = 0; j < 4; ++j)
                load16_to_lds(src + j * 256 + lane * 4, dst + j * 256);
            asm volatile("s_waitcnt vmcnt(4)" ::: "memory");
        } else {
            asm volatile("s_waitcnt vmcnt(0)" ::: "memory");
        }

        // ---- GEMV for this lane's row from LDS
        const float* vrow = &s_v[bb][rl * DIM];
        float acc[8];
        #pragma unroll
        for (int c8 = 0; c8 < 8; ++c8) acc[c8] = 0.0f;

        #pragma unroll
        for (int k = 0; k < KS; ++k) {
            float4 x = *(const float4*)&vrow[k * 128 + lg * 4];
            #pragma unroll
            for (int c8 = 0; c8 < 8; ++c8) {
                float4 wv = *(const float4*)&s_w[c8 * DIM + k * 128 + lg * 4];
                acc[c8] += dot4(wv, x);
            }
        }

        // reduce across the 32 lanes of the row-group
        #pragma unroll
        for (int c8 = 0; c8 < 8; ++c8) {
            float x2 = acc[c8];
            x2 += __shfl_xor(x2, 1);
            x2 += __shfl_xor(x2, 2);
            x2 += __shfl_xor(x2, 4);
            x2 += __shfl_xor(x2, 8);
            x2 += __shfl_xor(x2, 16);
            acc[c8] = x2;
        }

        // ---- epilogue: lane lg==0 of each group owns the row
        if (lg == 0) {
            const float area_r = (rbox.z - rbox.x) * (rbox.w - rbox.y);

            float biou = -1.0f; int bidx = 0;
            #pragma unroll
            for (int gi = 0; gi < G; ++gi) {
                float g0 = s_gt[gi * 4 + 0], g1 = s_gt[gi * 4 + 1];
                float g2 = s_gt[gi * 4 + 2], g3 = s_gt[gi * 4 + 3];
                float ltx = fmaxf(g0, rbox.x), lty = fmaxf(g1, rbox.y);
                float rbx = fminf(g2, rbox.z), rby = fminf(g3, rbox.w);
                float wx = fmaxf(rbx - ltx, 0.0f), wy = fmaxf(rby - lty, 0.0f);
                float inter = wx * wy;
                float ag = (g2 - g0) * (g3 - g1);
                float iou = inter / (ag + area_r - inter);
                if (iou > biou) { biou = iou; bidx = gi; }
            }
            const float mask = biou > 0.5f ? 1.0f : 0.0f;

            float c0 = fminf(fmaxf(acc[0] + cb0, 1e-7f), 0.99999994f);
            float c1 = fminf(fmaxf(acc[1] + cb1, 1e-7f), 0.99999994f);
            float c2 = fminf(fmaxf(acc[2] + cb2, 1e-7f), 0.99999994f);
            float c3 = fminf(fmaxf(acc[3] + cb3, 1e-7f), 0.99999994f);
            float m  = fmaxf(fmaxf(c0, c1), fmaxf(c2, c3));
            float s  = expf(c0 - m) + expf(c1 - m) + expf(c2 - m) + expf(c3 - m);
            float lse = m + logf(s);
            float csel = lab == 0 ? c0 : (lab == 1 ? c1 : (lab == 2 ? c2 : c3));
            float ce = lse - csel;

            acc_cnum += ce * ps * mask;
            acc_cden += mask;

            float bg0 = s_gt[bidx * 4 + 0], bg1 = s_gt[bidx * 4 + 1];
            float bg2 = s_gt[bidx * 4 + 2], bg3 = s_gt[bidx * 4 + 3];
            float gx = (bg2 + bg0) * 0.5f, gy = (bg3 + bg1) * 0.5f;
            float gw = (bg2 - bg0) * 0.5f, gh = (bg3 - bg1) * 0.5f;
            float rx = (rbox.z + rbox.x) * 0.5f, ry = (rbox.w + rbox.y) * 0.5f;
            float rw_ = (rbox.z - rbox.x) * 0.5f, rh = (rbox.w - rbox.y) * 0.5f;
            float tx = (gx - rx) / (rw_ + 1e-8f);
            float ty = (gy - ry) / (rh + 1e-8f);
            float tw = logf(gw / (rw_ + 1e-8f));
            float th = logf(gh / (rh + 1e-8f));
            float l1v = smooth_l1(acc[4] + rb0 - tx) + smooth_l1(acc[5] + rb1 - ty)
                      + smooth_l1(acc[6] + rb2 - tw) + smooth_l1(acc[7] + rb3 - th);
            acc_l1 += l1v * mask * ps;
        }
    }

    // ---- full-wave butterfly sum of the three partials
    #pragma unroll
    for (int off = 32; off > 0; off >>= 1) {
        acc_cnum += __shfl_xor(acc_cnum, off);
        acc_cden += __shfl_xor(acc_cden, off);
        acc_l1   += __shfl_xor(acc_l1,   off);
    }
    if (lane == 0) {
        s_red[w][0] = acc_cnum;
        s_red[w][1] = acc_cden;
        s_red[w][2] = acc_l1;
    }
    __syncthreads();
    if (tid == 0) {
        float a = 0.0f, bb2 = 0.0f, cc = 0.0f;
        #pragma unroll
        for (int wv = 0; wv < WAVES; ++wv) {
            a   += s_red[wv][0];
            bb2 += s_red[wv][1];
            cc  += s_red[wv][2];
        }
        atomicAdd(&partials[b * 3 + 0], a);
        atomicAdd(&partials[b * 3 + 1], bb2);
        atomicAdd(&partials[b * 3 + 2], cc);
    }
}

__global__ void det_final(const float* __restrict__ partials, float* __restrict__ out)
{
    if (threadIdx.x == 0 && blockIdx.x == 0) {
        float cl = 0.0f, l1 = 0.0f;
        #pragma unroll
        for (int b = 0; b < BS; ++b) {
            cl += partials[b * 3 + 0] / (partials[b * 3 + 1] + 1e-7f);
            l1 += partials[b * 3 + 2];
        }
        out[0] = cl / ((float)BS + 1e-7f) + l1 / (float)(BS * P);
    }
}

extern "C" void kernel_launch(void* const* d_in, const int* in_sizes, int n_in,
                              void* d_out, int out_size, void* d_ws, size_t ws_size,
                              hipStream_t stream) {
    const float* v         = (const float*)d_in[0];
    const float* gt        = (const float*)d_in[1];
    const float* rois      = (const float*)d_in[2];
    const float* labels    = (const float*)d_in[3];
    const float* pre_score = (const float*)d_in[4];
    const float* cls_w     = (const float*)d_in[5];
    const float* cls_b     = (const float*)d_in[6];
    const float* reg_w     = (const float*)d_in[7];
    const float* reg_b     = (const float*)d_in[8];
    float* partials = (float*)d_ws;
    float* out      = (float*)d_out;

    hipMemsetAsync(d_ws, 0, BS * 3 * sizeof(float), stream);
    det_main<<<(BS * P) / ROWS_PER_BLOCK, BLOCK, 0, stream>>>(
        v, gt, rois, labels, pre_score, cls_w, cls_b, reg_w, reg_b, partials);
    det_final<<<1, 64, 0, stream>>>(partials, out);
}

// Round 9
// 44.676 us; speedup vs baseline: 2.7582x; 1.9445x over previous
//
#include <hip/hip_runtime.h>
#include <math.h>

#define BS 8
#define P 8192
#define G 16
#define DIM 512

#define BLOCK 256
#define WAVES 4
#define RPG 4                                   // rows per 8-lane group
#define ROWS_PER_WAVE 32                        // 8 groups x RPG
#define ROWS_PER_BLOCK (WAVES * ROWS_PER_WAVE)  // 128
#define BLOCKS_PER_BATCH (P / ROWS_PER_BLOCK)   // 64 -> grid 512 = 2 blocks/CU
#define KC 32                                   // cols per k-chunk
#define NKC (DIM / KC)                          // 16 chunks
#define CHUNK_FLOATS (ROWS_PER_WAVE * KC)       // 1024 floats = 4 KB

__device__ __forceinline__ float smooth_l1(float d) {
    float a = fabsf(d);
    return a < 1.0f ? 0.5f * d * d : a - 0.5f;
}

__device__ __forceinline__ float dot4(float4 a, float4 b) {
    return a.x * b.x + a.y * b.y + a.z * b.z + a.w * b.w;
}

// Fire-and-forget global->LDS DMA, 16B/lane; LDS dest = uniform base + lane*16.
__device__ __forceinline__ void load16_to_lds(const float* gsrc, float* ldst) {
    __builtin_amdgcn_global_load_lds(
        (const __attribute__((address_space(1))) void*)gsrc,
        (__attribute__((address_space(3))) void*)ldst,
        16, 0, 0);
}

// Stage one 32-row x 32-col k-chunk (4 KB) of this wave's rows: 4 issues,
// issue j covers rows j*8..j*8+7 (8 lanes per 128B row-slice). LDS dest is
// linear [32][32] row-major, as global_load_lds requires.
__device__ __forceinline__ void stage_chunk(const float* __restrict__ vwave,
                                            int kc, float* dst, int lane) {
    const float* src0 = vwave + (size_t)kc * KC + (size_t)(lane >> 3) * DIM + (lane & 7) * 4;
    #pragma unroll
    for (int j = 0; j < 4; ++j)
        load16_to_lds(src0 + (size_t)j * 8 * DIM, dst + j * 256);
}

// launch_bounds (256,1): no VGPR clamp (",4"/",2" caused 10-421 MB scratch
// spills in r2-r4). Occupancy is LDS-limited: ~68 KB -> 2 blocks/CU.
__global__ __launch_bounds__(BLOCK, 1)
void det_main(const float* __restrict__ v,
              const float* __restrict__ gt,
              const float* __restrict__ rois,
              const float* __restrict__ labels,
              const float* __restrict__ pre_score,
              const float* __restrict__ cls_w,
              const float* __restrict__ cls_b,
              const float* __restrict__ reg_w,
              const float* __restrict__ reg_b,
              float* __restrict__ partials)   // [BS][3]: cnum, cden, l1
{
    const int tid  = threadIdx.x;
    const int lane = tid & 63;
    const int w    = tid >> 6;      // wave 0..3
    const int grp  = lane >> 3;     // 8-lane group 0..7
    const int l    = lane & 7;      // lane within group
    const int b    = blockIdx.x / BLOCKS_PER_BATCH;
    const int blk  = blockIdx.x % BLOCKS_PER_BATCH;
    const int p0   = blk * ROWS_PER_BLOCK;
    const int wrow0 = p0 + w * ROWS_PER_WAVE;   // this wave's first row

    __shared__ float s_w[8 * DIM];                       // 16 KB weights
    __shared__ float s_v[WAVES][3][CHUNK_FLOATS];        // 48 KB, 3-buf/wave
    __shared__ float s_rois[ROWS_PER_BLOCK * 4];         // 2 KB
    __shared__ float s_ps[ROWS_PER_BLOCK];               // 0.5 KB
    __shared__ float s_gt[G * 4];
    __shared__ float s_red[WAVES][3];

    const float* vwave = v + ((size_t)b * P + wrow0) * DIM;

    // ---- label argmax: uniform, computed redundantly by every thread
    const float* lb = labels + b * 4;
    int lab = 0; float lm = lb[0];
    { float t = lb[1]; if (t > lm) { lm = t; lab = 1; } }
    { float t = lb[2]; if (t > lm) { lm = t; lab = 2; } }
    { float t = lb[3]; if (t > lm) { lm = t; lab = 3; } }

    // ---- issue DMA for chunks 0,1 first (latency hides under staging below)
    stage_chunk(vwave, 0, &s_v[w][0][0], lane);
    stage_chunk(vwave, 1, &s_v[w][1][0], lane);

    // ---- stage weights (16 KB), rois (2 KB), ps (0.5 KB), gt
    {
        const float4* cw = (const float4*)cls_w;   // 512 float4
        const float4* rw = (const float4*)reg_w;   // 512 float4
        float4* sw = (float4*)s_w;
        sw[tid]       = cw[tid];
        sw[256 + tid] = cw[256 + tid];
        sw[512 + tid] = rw[tid];
        sw[768 + tid] = rw[256 + tid];
    }
    if (tid < ROWS_PER_BLOCK) {
        ((float4*)s_rois)[tid] = ((const float4*)rois)[(size_t)b * P + p0 + tid];
        s_ps[tid] = pre_score[((size_t)b * P + p0 + tid) * 4 + lab];
    }
    if (tid < G * 4) s_gt[tid] = gt[b * G * 4 + tid];
    __syncthreads();   // drains prologue (incl. chunk 0,1 DMA) -> vmcnt = 0

    const float cb0 = cls_b[0], cb1 = cls_b[1], cb2 = cls_b[2], cb3 = cls_b[3];
    const float rb0 = reg_b[0], rb1 = reg_b[1], rb2 = reg_b[2], rb3 = reg_b[3];

    // ---- main loop: 16 k-chunks, triple-buffered, counted vmcnt (never 0
    // until the last chunk). No block barriers: chunks are wave-private.
    float acc[8][RPG];
    #pragma unroll
    for (int c = 0; c < 8; ++c)
        #pragma unroll
        for (int r = 0; r < RPG; ++r) acc[c][r] = 0.0f;

    int cur = 0;
    #pragma unroll 1
    for (int kc = 0; kc < NKC; ++kc) {
        // chunk kc guaranteed arrived: <=1 chunk (4 issues) stays in flight
        if (kc == NKC - 1) asm volatile("s_waitcnt vmcnt(0)" ::: "memory");
        else               asm volatile("s_waitcnt vmcnt(4)" ::: "memory");

        const float* vb = &s_v[w][cur][(grp * RPG) * KC + l * 4];
        float4 x0 = *(const float4*)(vb + 0 * KC);
        float4 x1 = *(const float4*)(vb + 1 * KC);
        float4 x2 = *(const float4*)(vb + 2 * KC);
        float4 x3 = *(const float4*)(vb + 3 * KC);
        // weight reads broadcast across the 8 groups (addr depends on l only)
        #pragma unroll
        for (int c = 0; c < 8; ++c) {
            float4 wv = *(const float4*)&s_w[c * DIM + kc * KC + l * 4];
            acc[c][0] += dot4(wv, x0);
            acc[c][1] += dot4(wv, x1);
            acc[c][2] += dot4(wv, x2);
            acc[c][3] += dot4(wv, x3);
        }
        // refill: kc+2 goes into the third buffer (never the one being read
        // this iter nor the in-flight one) -> no DMA/ds_read WAR race
        if (kc < NKC - 2) {
            int nxt = cur + 2; if (nxt >= 3) nxt -= 3;
            stage_chunk(vwave, kc + 2, &s_v[w][nxt][0], lane);
        }
        ++cur; if (cur == 3) cur = 0;
    }

    // ---- reduce across the 8 lanes of each group (3 butterfly steps)
    #pragma unroll
    for (int c = 0; c < 8; ++c)
        #pragma unroll
        for (int r = 0; r < RPG; ++r) {
            float x = acc[c][r];
            x += __shfl_xor(x, 1);
            x += __shfl_xor(x, 2);
            x += __shfl_xor(x, 4);
            acc[c][r] = x;
        }

    // ---- epilogue: lane l (<RPG) of each group handles its group's row l
    float acc_cnum = 0.0f, acc_cden = 0.0f, acc_l1 = 0.0f;
    if (l < RPG) {
        float d[8];
        #pragma unroll
        for (int r = 0; r < RPG; ++r)
            if (l == r) {
                #pragma unroll
                for (int c = 0; c < 8; ++c) d[c] = acc[c][r];
            }
        const int lrow = w * ROWS_PER_WAVE + grp * RPG + l;  // block-local row
        const float4 rbox = *(const float4*)&s_rois[lrow * 4];
        const float ps = s_ps[lrow];
        const float area_r = (rbox.z - rbox.x) * (rbox.w - rbox.y);

        float biou = -1.0f; int bidx = 0;
        #pragma unroll
        for (int gi = 0; gi < G; ++gi) {
            float g0 = s_gt[gi * 4 + 0], g1 = s_gt[gi * 4 + 1];
            float g2 = s_gt[gi * 4 + 2], g3 = s_gt[gi * 4 + 3];
            float ltx = fmaxf(g0, rbox.x), lty = fmaxf(g1, rbox.y);
            float rbx = fminf(g2, rbox.z), rby = fminf(g3, rbox.w);
            float wx = fmaxf(rbx - ltx, 0.0f), wy = fmaxf(rby - lty, 0.0f);
            float inter = wx * wy;
            float ag = (g2 - g0) * (g3 - g1);
            float iou = inter / (ag + area_r - inter);
            if (iou > biou) { biou = iou; bidx = gi; }
        }
        const float mask = biou > 0.5f ? 1.0f : 0.0f;

        // cross-entropy on clipped logits
        float c0 = fminf(fmaxf(d[0] + cb0, 1e-7f), 0.99999994f);
        float c1 = fminf(fmaxf(d[1] + cb1, 1e-7f), 0.99999994f);
        float c2 = fminf(fmaxf(d[2] + cb2, 1e-7f), 0.99999994f);
        float c3 = fminf(fmaxf(d[3] + cb3, 1e-7f), 0.99999994f);
        float m  = fmaxf(fmaxf(c0, c1), fmaxf(c2, c3));
        float s  = expf(c0 - m) + expf(c1 - m) + expf(c2 - m) + expf(c3 - m);
        float lse = m + logf(s);
        float csel = lab == 0 ? c0 : (lab == 1 ? c1 : (lab == 2 ? c2 : c3));
        float ce = lse - csel;

        acc_cnum = ce * ps * mask;
        acc_cden = mask;

        // regression loss vs best-GT targets
        float bg0 = s_gt[bidx * 4 + 0], bg1 = s_gt[bidx * 4 + 1];
        float bg2 = s_gt[bidx * 4 + 2], bg3 = s_gt[bidx * 4 + 3];
        float gx = (bg2 + bg0) * 0.5f, gy = (bg3 + bg1) * 0.5f;
        float gw = (bg2 - bg0) * 0.5f, gh = (bg3 - bg1) * 0.5f;
        float rx = (rbox.z + rbox.x) * 0.5f, ry = (rbox.w + rbox.y) * 0.5f;
        float rw_ = (rbox.z - rbox.x) * 0.5f, rh = (rbox.w - rbox.y) * 0.5f;
        float tx = (gx - rx) / (rw_ + 1e-8f);
        float ty = (gy - ry) / (rh + 1e-8f);
        float tw = logf(gw / (rw_ + 1e-8f));
        float th = logf(gh / (rh + 1e-8f));
        float l1v = smooth_l1(d[4] + rb0 - tx) + smooth_l1(d[5] + rb1 - ty)
                  + smooth_l1(d[6] + rb2 - tw) + smooth_l1(d[7] + rb3 - th);
        acc_l1 = l1v * mask * ps;
    }

    // ---- full-wave butterfly sum of the three partials
    #pragma unroll
    for (int off = 32; off > 0; off >>= 1) {
        acc_cnum += __shfl_xor(acc_cnum, off);
        acc_cden += __shfl_xor(acc_cden, off);
        acc_l1   += __shfl_xor(acc_l1,   off);
    }
    if (lane == 0) {
        s_red[w][0] = acc_cnum;
        s_red[w][1] = acc_cden;
        s_red[w][2] = acc_l1;
    }
    __syncthreads();
    if (tid == 0) {
        float a = 0.0f, bb = 0.0f, cc = 0.0f;
        #pragma unroll
        for (int wv = 0; wv < WAVES; ++wv) {
            a  += s_red[wv][0];
            bb += s_red[wv][1];
            cc += s_red[wv][2];
        }
        atomicAdd(&partials[b * 3 + 0], a);
        atomicAdd(&partials[b * 3 + 1], bb);
        atomicAdd(&partials[b * 3 + 2], cc);
    }
}

__global__ void det_final(const float* __restrict__ partials, float* __restrict__ out)
{
    if (threadIdx.x == 0 && blockIdx.x == 0) {
        float cl = 0.0f, l1 = 0.0f;
        #pragma unroll
        for (int b = 0; b < BS; ++b) {
            cl += partials[b * 3 + 0] / (partials[b * 3 + 1] + 1e-7f);
            l1 += partials[b * 3 + 2];
        }
        out[0] = cl / ((float)BS + 1e-7f) + l1 / (float)(BS * P);
    }
}

extern "C" void kernel_launch(void* const* d_in, const int* in_sizes, int n_in,
                              void* d_out, int out_size, void* d_ws, size_t ws_size,
                              hipStream_t stream) {
    const float* v         = (const float*)d_in[0];
    const float* gt        = (const float*)d_in[1];
    const float* rois      = (const float*)d_in[2];
    const float* labels    = (const float*)d_in[3];
    const float* pre_score = (const float*)d_in[4];
    const float* cls_w     = (const float*)d_in[5];
    const float* cls_b     = (const float*)d_in[6];
    const float* reg_w     = (const float*)d_in[7];
    const float* reg_b     = (const float*)d_in[8];
    float* partials = (float*)d_ws;
    float* out      = (float*)d_out;

    hipMemsetAsync(d_ws, 0, BS * 3 * sizeof(float), stream);
    det_main<<<(BS * P) / ROWS_PER_BLOCK, BLOCK, 0, stream>>>(
        v, gt, rois, labels, pre_score, cls_w, cls_b, reg_w, reg_b, partials);
    det_final<<<1, 64, 0, stream>>>(partials, out);
}